// Round 2
// baseline (200.954 us; speedup 1.0000x reference)
//
#include <hip/hip_runtime.h>

// SmoothL1 (beta=0.5) masked sum reduction, N = 16M fixed.
// sl1 = ad < 0.5 ? d*d : ad - 0.25  (0.5*d*d/0.5 == d*d exactly: pow-2)
// mask: ad >= 1.0f/len; out[0] = sum(mask ? sl1 : 0)
//
// R1 -> R2: latency-bound at VGPR=20 (compiler serialized loads, vmcnt(0)
// per iteration). Fix: unroll x4, batch 12 independent dwordx4 loads into
// register arrays before any consuming wait. Block-contiguous partition:
// block b owns vec4 indices [b*1024, (b+1)*1024), thread t handles
// t, t+256, t+512, t+768 -> coalesced 16B/lane across the wave.

#define N_TOTAL 16777216
#define NVEC    (N_TOTAL / 4)   // 4194304 float4 groups
#define UNROLL  4
#define BLOCK   256
#define GRID    (NVEC / (BLOCK * UNROLL))   // 4096 blocks, exact cover

__device__ __forceinline__ float sl1_term(float o, float l, int len) {
    float d  = o - l;
    float ad = fabsf(d);
    float v  = (ad < 0.5f) ? (d * d) : (ad - 0.25f);
    float boundary = 1.0f / (float)len;   // IEEE divide; matches jnp 1/len
    return (ad >= boundary) ? v : 0.0f;
}

__global__ __launch_bounds__(BLOCK) void RegressionLoss_45440753992375_kernel(
        const float* __restrict__ outs,
        const float* __restrict__ labels,
        const int*   __restrict__ lens,
        float* __restrict__ out) {
    const float4* o4 = (const float4*)outs;
    const float4* l4 = (const float4*)labels;
    const int4*   n4 = (const int4*)lens;

    const int base = blockIdx.x * (BLOCK * UNROLL) + threadIdx.x;

    // Batch all loads first: 12 independent global_load_dwordx4 in flight.
    float4 o[UNROLL], l[UNROLL];
    int4   ln[UNROLL];
    #pragma unroll
    for (int u = 0; u < UNROLL; ++u) o[u]  = o4[base + u * BLOCK];
    #pragma unroll
    for (int u = 0; u < UNROLL; ++u) l[u]  = l4[base + u * BLOCK];
    #pragma unroll
    for (int u = 0; u < UNROLL; ++u) ln[u] = n4[base + u * BLOCK];

    float acc = 0.0f;
    #pragma unroll
    for (int u = 0; u < UNROLL; ++u) {
        acc += sl1_term(o[u].x, l[u].x, ln[u].x);
        acc += sl1_term(o[u].y, l[u].y, ln[u].y);
        acc += sl1_term(o[u].z, l[u].z, ln[u].z);
        acc += sl1_term(o[u].w, l[u].w, ln[u].w);
    }

    // wave-64 shuffle reduction
    #pragma unroll
    for (int off = 32; off > 0; off >>= 1)
        acc += __shfl_down(acc, off, 64);

    __shared__ float smem[BLOCK / 64];
    const int lane = threadIdx.x & 63;
    const int wid  = threadIdx.x >> 6;
    if (lane == 0) smem[wid] = acc;
    __syncthreads();
    if (threadIdx.x == 0) {
        float bsum = smem[0] + smem[1] + smem[2] + smem[3];
        atomicAdd(out, bsum);   // device-scope by default on CDNA
    }
}

extern "C" void kernel_launch(void* const* d_in, const int* in_sizes, int n_in,
                              void* d_out, int out_size, void* d_ws, size_t ws_size,
                              hipStream_t stream) {
    const float* outs   = (const float*)d_in[0];
    const float* labels = (const float*)d_in[1];
    const int*   lens   = (const int*)d_in[2];
    float* out = (float*)d_out;

    // d_out is poisoned 0xAA before every timed launch — zero it on-stream.
    hipMemsetAsync(out, 0, sizeof(float), stream);

    RegressionLoss_45440753992375_kernel<<<GRID, BLOCK, 0, stream>>>(outs, labels, lens, out);
}

// Round 3
// 195.865 us; speedup vs baseline: 1.0260x; 1.0260x over previous
//
#include <hip/hip_runtime.h>

// SmoothL1 (beta=0.5) masked sum reduction, N = 16M fixed.
// sl1 = ad < 0.5 ? d*d : ad - 0.25  (0.5*d*d/0.5 == d*d exactly: pow-2)
// mask: ad >= 1.0f/len; out[0] = sum(mask ? sl1 : 0)
//
// R2 -> R3: evidence says service-rate cap ~2.76 TB/s read (effective), not MLP.
// This round is the discriminating experiment: persistent 2048 blocks
// (8 blocks/CU = full 32 waves/CU) + explicit software-pipelined prefetch
// (next iteration's 3 loads issued before current consumption), so >=3-6
// 1KB loads are continuously in flight per wave. Block-contiguous layout:
// block b owns vec4 range [b*2048, (b+1)*2048) => 32 KB/stream/block.

#define N_TOTAL 16777216
#define NVEC    (N_TOTAL / 4)       // 4194304 vec4 groups
#define BLOCK   256
#define GRID    2048                // 8 blocks/CU on 256 CUs
#define ITERS   (NVEC / (BLOCK * GRID))   // 8 iterations/thread, exact cover

__device__ __forceinline__ float sl1_term(float o, float l, int len) {
    float d  = o - l;
    float ad = fabsf(d);
    float v  = (ad < 0.5f) ? (d * d) : (ad - 0.25f);
    float boundary = 1.0f / (float)len;   // IEEE divide; matches jnp 1/len
    return (ad >= boundary) ? v : 0.0f;
}

__global__ __launch_bounds__(BLOCK) void RegressionLoss_45440753992375_kernel(
        const float* __restrict__ outs,
        const float* __restrict__ labels,
        const int*   __restrict__ lens,
        float* __restrict__ out) {
    const float4* o4 = (const float4*)outs;
    const float4* l4 = (const float4*)labels;
    const int4*   n4 = (const int4*)lens;

    // Block-contiguous: block b owns [b*BLOCK*ITERS, ...), thread strides BLOCK.
    int i = blockIdx.x * (BLOCK * ITERS) + threadIdx.x;

    // Software pipeline: stage 0 loads issued here.
    float4 o_c = o4[i];
    float4 l_c = l4[i];
    int4   n_c = n4[i];

    float acc = 0.0f;
    #pragma unroll
    for (int it = 0; it < ITERS - 1; ++it) {
        i += BLOCK;
        // Issue next-iteration loads BEFORE consuming current registers:
        // keeps 3-6 dwordx4 loads in flight per wave continuously.
        float4 o_n = o4[i];
        float4 l_n = l4[i];
        int4   n_n = n4[i];

        acc += sl1_term(o_c.x, l_c.x, n_c.x);
        acc += sl1_term(o_c.y, l_c.y, n_c.y);
        acc += sl1_term(o_c.z, l_c.z, n_c.z);
        acc += sl1_term(o_c.w, l_c.w, n_c.w);

        o_c = o_n; l_c = l_n; n_c = n_n;
    }
    acc += sl1_term(o_c.x, l_c.x, n_c.x);
    acc += sl1_term(o_c.y, l_c.y, n_c.y);
    acc += sl1_term(o_c.z, l_c.z, n_c.z);
    acc += sl1_term(o_c.w, l_c.w, n_c.w);

    // wave-64 shuffle reduction
    #pragma unroll
    for (int off = 32; off > 0; off >>= 1)
        acc += __shfl_down(acc, off, 64);

    __shared__ float smem[BLOCK / 64];
    const int lane = threadIdx.x & 63;
    const int wid  = threadIdx.x >> 6;
    if (lane == 0) smem[wid] = acc;
    __syncthreads();
    if (threadIdx.x == 0) {
        float bsum = smem[0] + smem[1] + smem[2] + smem[3];
        atomicAdd(out, bsum);   // device-scope by default on CDNA
    }
}

extern "C" void kernel_launch(void* const* d_in, const int* in_sizes, int n_in,
                              void* d_out, int out_size, void* d_ws, size_t ws_size,
                              hipStream_t stream) {
    const float* outs   = (const float*)d_in[0];
    const float* labels = (const float*)d_in[1];
    const int*   lens   = (const int*)d_in[2];
    float* out = (float*)d_out;

    // d_out is poisoned 0xAA before every timed launch — zero it on-stream.
    hipMemsetAsync(out, 0, sizeof(float), stream);

    RegressionLoss_45440753992375_kernel<<<GRID, BLOCK, 0, stream>>>(outs, labels, lens, out);
}

// Round 4
// 187.804 us; speedup vs baseline: 1.0700x; 1.0429x over previous
//
#include <hip/hip_runtime.h>

// SmoothL1 (beta=0.5) masked sum reduction, N = 16M fixed.
// sl1 = ad < 0.5 ? d*d : ad - 0.25  (0.5*d*d/0.5 == d*d exactly: pow-2)
// mask: ad >= 1.0f/len; out[0] = sum(mask ? sl1 : 0)
//
// R3 -> R4: plateau at 73-78 us across naive/batched/pipelined structures and
// invariant to HBM-vs-L3 sourcing => read-path service cap ~2.7 TB/s effective,
// not wave MLP. Last mechanism test: non-temporal (no-allocate/evict-first)
// loads on the fastest structure (R1 grid-stride). If cache write-allocation
// of streamed lines was stealing service BW, nt relieves it; if it's a
// fabric/queue service cap, this is neutral and we're at the roofline.

#define N_TOTAL 16777216
#define NVEC    (N_TOTAL / 4)
#define BLOCK   256
#define GRID    2048   // 8 blocks/CU, 32 waves/CU

typedef float f32x4 __attribute__((ext_vector_type(4)));
typedef int   i32x4 __attribute__((ext_vector_type(4)));

__device__ __forceinline__ float sl1_term(float o, float l, int len) {
    float d  = o - l;
    float ad = fabsf(d);
    float v  = (ad < 0.5f) ? (d * d) : (ad - 0.25f);
    float boundary = 1.0f / (float)len;   // IEEE divide; matches jnp 1/len
    return (ad >= boundary) ? v : 0.0f;
}

__global__ __launch_bounds__(BLOCK) void RegressionLoss_45440753992375_kernel(
        const float* __restrict__ outs,
        const float* __restrict__ labels,
        const int*   __restrict__ lens,
        float* __restrict__ out) {
    const int tid    = blockIdx.x * BLOCK + threadIdx.x;
    const int stride = GRID * BLOCK;

    const f32x4* o4 = (const f32x4*)outs;
    const f32x4* l4 = (const f32x4*)labels;
    const i32x4* n4 = (const i32x4*)lens;

    float acc = 0.0f;
    for (int i = tid; i < NVEC; i += stride) {
        f32x4 o  = __builtin_nontemporal_load(o4 + i);
        f32x4 l  = __builtin_nontemporal_load(l4 + i);
        i32x4 ln = __builtin_nontemporal_load(n4 + i);
        acc += sl1_term(o.x, l.x, ln.x);
        acc += sl1_term(o.y, l.y, ln.y);
        acc += sl1_term(o.z, l.z, ln.z);
        acc += sl1_term(o.w, l.w, ln.w);
    }

    // wave-64 shuffle reduction
    #pragma unroll
    for (int off = 32; off > 0; off >>= 1)
        acc += __shfl_down(acc, off, 64);

    __shared__ float smem[BLOCK / 64];
    const int lane = threadIdx.x & 63;
    const int wid  = threadIdx.x >> 6;
    if (lane == 0) smem[wid] = acc;
    __syncthreads();
    if (threadIdx.x == 0) {
        float bsum = smem[0] + smem[1] + smem[2] + smem[3];
        atomicAdd(out, bsum);   // device-scope by default on CDNA
    }
}

extern "C" void kernel_launch(void* const* d_in, const int* in_sizes, int n_in,
                              void* d_out, int out_size, void* d_ws, size_t ws_size,
                              hipStream_t stream) {
    const float* outs   = (const float*)d_in[0];
    const float* labels = (const float*)d_in[1];
    const int*   lens   = (const int*)d_in[2];
    float* out = (float*)d_out;

    // d_out is poisoned 0xAA before every timed launch — zero it on-stream.
    hipMemsetAsync(out, 0, sizeof(float), stream);

    RegressionLoss_45440753992375_kernel<<<GRID, BLOCK, 0, stream>>>(outs, labels, lens, out);
}

// Round 5
// 186.898 us; speedup vs baseline: 1.0752x; 1.0048x over previous
//
#include <hip/hip_runtime.h>

// SmoothL1 (beta=0.5) masked sum reduction, N = 16M fixed.
// sl1 = ad < 0.5 ? d*d : ad - 0.25  (0.5*d*d/0.5 == d*d exactly: pow-2)
// mask: ad >= 1.0f/len; out[0] = sum(mask ? sl1 : 0)
//
// R4 -> R5: nt loads broke the 73us plateau (cache write-allocation was the
// throttle) -> 49us, 4.1 TB/s effective read. Now re-test MLP in the new
// regime: persistent blocks + explicit software-pipelined nt loads (next
// iteration's 3 dwordx4 issued before current consumption), so the wave never
// drains vmcnt to 0 between iterations.

#define N_TOTAL 16777216
#define NVEC    (N_TOTAL / 4)       // 4194304 vec4 groups
#define BLOCK   256
#define GRID    2048                // 8 blocks/CU, 32 waves/CU
#define ITERS   (NVEC / (BLOCK * GRID))   // 8 iterations/thread, exact cover

typedef float f32x4 __attribute__((ext_vector_type(4)));
typedef int   i32x4 __attribute__((ext_vector_type(4)));

__device__ __forceinline__ float sl1_term(float o, float l, int len) {
    float d  = o - l;
    float ad = fabsf(d);
    float v  = (ad < 0.5f) ? (d * d) : (ad - 0.25f);
    float boundary = 1.0f / (float)len;   // IEEE divide; matches jnp 1/len
    return (ad >= boundary) ? v : 0.0f;
}

__global__ __launch_bounds__(BLOCK) void RegressionLoss_45440753992375_kernel(
        const float* __restrict__ outs,
        const float* __restrict__ labels,
        const int*   __restrict__ lens,
        float* __restrict__ out) {
    const f32x4* o4 = (const f32x4*)outs;
    const f32x4* l4 = (const f32x4*)labels;
    const i32x4* n4 = (const i32x4*)lens;

    // Block-contiguous: block b owns [b*BLOCK*ITERS, ...), thread strides BLOCK.
    int i = blockIdx.x * (BLOCK * ITERS) + threadIdx.x;

    // Pipeline stage 0.
    f32x4 o_c = __builtin_nontemporal_load(o4 + i);
    f32x4 l_c = __builtin_nontemporal_load(l4 + i);
    i32x4 n_c = __builtin_nontemporal_load(n4 + i);

    float acc = 0.0f;
    #pragma unroll
    for (int it = 0; it < ITERS - 1; ++it) {
        i += BLOCK;
        // Issue next-iteration nt loads BEFORE consuming current registers.
        f32x4 o_n = __builtin_nontemporal_load(o4 + i);
        f32x4 l_n = __builtin_nontemporal_load(l4 + i);
        i32x4 n_n = __builtin_nontemporal_load(n4 + i);

        acc += sl1_term(o_c.x, l_c.x, n_c.x);
        acc += sl1_term(o_c.y, l_c.y, n_c.y);
        acc += sl1_term(o_c.z, l_c.z, n_c.z);
        acc += sl1_term(o_c.w, l_c.w, n_c.w);

        o_c = o_n; l_c = l_n; n_c = n_n;
    }
    acc += sl1_term(o_c.x, l_c.x, n_c.x);
    acc += sl1_term(o_c.y, l_c.y, n_c.y);
    acc += sl1_term(o_c.z, l_c.z, n_c.z);
    acc += sl1_term(o_c.w, l_c.w, n_c.w);

    // wave-64 shuffle reduction
    #pragma unroll
    for (int off = 32; off > 0; off >>= 1)
        acc += __shfl_down(acc, off, 64);

    __shared__ float smem[BLOCK / 64];
    const int lane = threadIdx.x & 63;
    const int wid  = threadIdx.x >> 6;
    if (lane == 0) smem[wid] = acc;
    __syncthreads();
    if (threadIdx.x == 0) {
        float bsum = smem[0] + smem[1] + smem[2] + smem[3];
        atomicAdd(out, bsum);   // device-scope by default on CDNA
    }
}

extern "C" void kernel_launch(void* const* d_in, const int* in_sizes, int n_in,
                              void* d_out, int out_size, void* d_ws, size_t ws_size,
                              hipStream_t stream) {
    const float* outs   = (const float*)d_in[0];
    const float* labels = (const float*)d_in[1];
    const int*   lens   = (const int*)d_in[2];
    float* out = (float*)d_out;

    // d_out is poisoned 0xAA before every timed launch — zero it on-stream.
    hipMemsetAsync(out, 0, sizeof(float), stream);

    RegressionLoss_45440753992375_kernel<<<GRID, BLOCK, 0, stream>>>(outs, labels, lens, out);
}